// Round 3
// baseline (6686.401 us; speedup 1.0000x reference)
//
#include <hip/hip_runtime.h>

#define AS1 __attribute__((address_space(1)))
#define AS3 __attribute__((address_space(3)))

using f32x4  = __attribute__((ext_vector_type(4))) float;
using bf16x8 = __attribute__((ext_vector_type(8))) __bf16;

// ---- ViT-B/16 constants (B=32) ----
#define LAYERS 12
#define DIM    768
#define HIDDEN 3072
#define NHEAD  12
#define HSZ    64
#define BATCH  32
#define NPATCH 196
#define SEQ    197
#define MREAL  (BATCH*SEQ)      // 6304
#define MPAD   6400             // 50*128
#define MPATCH (BATCH*NPATCH)   // 6272 = 49*128
#define QKVN   (3*DIM)          // 2304
#define KN     (DIM*DIM)

static __device__ __forceinline__ unsigned short f2b(float f){
  unsigned int u = __float_as_uint(f);
  u = (u + 0x7FFFu + ((u >> 16) & 1u)) >> 16;   // RNE to bf16
  return (unsigned short)u;
}

static __device__ __forceinline__ void gl_lds16(const unsigned short* g, unsigned short* l){
  // 16B-wide async global->LDS; LDS dest pattern = wave base + lane*16 (linear)
  __builtin_amdgcn_global_load_lds((AS1 void*)g, (AS3 void*)l, 16, 0, 0);
}

// ---------------- weight prep ----------------
// src [Lz][K][N] f32 row-major -> dst per-layer [N][K] bf16 ("B^T" for gemm_bt)
__global__ void transpose_cast(const float* __restrict__ src, unsigned short* __restrict__ dst,
                               int K, int N, size_t sls, size_t dls){
  __shared__ float tile[32][33];
  const int l  = blockIdx.z;
  const int k0 = blockIdx.x * 32;
  const int n0 = blockIdx.y * 32;
  const float* s = src + (size_t)l * sls;
  unsigned short* d = dst + (size_t)l * dls;
  const int tx = threadIdx.x & 31, ty = threadIdx.x >> 5;   // 32 x 8
#pragma unroll
  for (int r = 0; r < 32; r += 8)
    tile[ty + r][tx] = s[(size_t)(k0 + ty + r) * N + n0 + tx];
  __syncthreads();
#pragma unroll
  for (int r = 0; r < 32; r += 8)
    d[(size_t)(n0 + ty + r) * K + k0 + tx] = f2b(tile[tx][ty + r]);
}

__global__ void cast_bf16(const float* __restrict__ s, unsigned short* __restrict__ d, int n){
  int i = blockIdx.x * 256 + threadIdx.x;
  if (i < n) d[i] = f2b(s[i]);
}

__global__ void pack_bias(const float* __restrict__ bq, const float* __restrict__ bk,
                          const float* __restrict__ bv, float* __restrict__ dst){
  int i = blockIdx.x * 256 + threadIdx.x;
  if (i >= LAYERS * QKVN) return;
  int l = i / QKVN, c = i % QKVN;
  float v = (c < DIM) ? bq[l*DIM + c] : (c < 2*DIM) ? bk[l*DIM + c - DIM] : bv[l*DIM + c - 2*DIM];
  dst[i] = v;
}

// ---------------- patch embed ----------------
// patches_bf16[b*196+p][c*256+i*16+j] = x[b][c][pr*16+i][pc*16+j]
__global__ void patchify(const float* __restrict__ x, unsigned short* __restrict__ pat){
  const int row = blockIdx.x;                       // b*196+p
  const int cc  = blockIdx.y * 256 + threadIdx.x;   // 0..767
  const int b = row / NPATCH, p = row % NPATCH;
  const int c = cc >> 8, rem = cc & 255, ii = rem >> 4, jj = rem & 15;
  const int pr = p / 14, pc = p % 14;
  float v = x[(((size_t)(b*3 + c) * 224) + pr*16 + ii) * 224 + pc*16 + jj];
  pat[(size_t)row * DIM + cc] = f2b(v);
}

// h[b*197+p] = (p==0 ? cls : patch_gemm_out[b*196+p-1]) + pos[p]
__global__ void assemble(const float* __restrict__ yq, const float* __restrict__ cls,
                         const float* __restrict__ pos, float* __restrict__ h){
  const int row = blockIdx.x;                       // 0..6303
  const int d   = blockIdx.y * 256 + threadIdx.x;
  const int b = row / SEQ, p = row % SEQ;
  float v = (p == 0) ? cls[d] : yq[(size_t)(b*NPATCH + p - 1) * DIM + d];
  h[(size_t)row * DIM + d] = v + pos[p*DIM + d];
}

// ---------------- layernorm (f32 in, bf16 out) ----------------
__global__ __launch_bounds__(256) void ln_bf16(const float* __restrict__ h,
                const float* __restrict__ w, const float* __restrict__ b,
                unsigned short* __restrict__ out, int nrows){
  const int wave = threadIdx.x >> 6, lane = threadIdx.x & 63;
  const int row = blockIdx.x * 4 + wave;
  if (row >= nrows) return;
  const float* p = h + (size_t)row * DIM;
  float4 v[3]; float s = 0.f, ss = 0.f;
#pragma unroll
  for (int t = 0; t < 3; t++){
    v[t] = *(const float4*)&p[lane*4 + t*256];
    s  += v[t].x + v[t].y + v[t].z + v[t].w;
    ss += v[t].x*v[t].x + v[t].y*v[t].y + v[t].z*v[t].z + v[t].w*v[t].w;
  }
#pragma unroll
  for (int off = 32; off; off >>= 1){ s += __shfl_xor(s, off); ss += __shfl_xor(ss, off); }
  const float mean = s * (1.f/DIM);
  const float inv  = rsqrtf(ss * (1.f/DIM) - mean*mean + 1e-5f);
#pragma unroll
  for (int t = 0; t < 3; t++){
    const int c = lane*4 + t*256;
    float4 wv = *(const float4*)&w[c];
    float4 bv = *(const float4*)&b[c];
    ushort4 o;
    o.x = f2b((v[t].x - mean)*inv*wv.x + bv.x);
    o.y = f2b((v[t].y - mean)*inv*wv.y + bv.y);
    o.z = f2b((v[t].z - mean)*inv*wv.z + bv.z);
    o.w = f2b((v[t].w - mean)*inv*wv.w + bv.w);
    *(ushort4*)&out[(size_t)row * DIM + c] = o;
  }
}

// ---------------- GEMM: C[M,N] = A[M,K](bf16) @ Bt[N,K](bf16)^T + bias (+epilogue) ----------------
// m97 structure: 128x128 tile, BK=32, 4 waves (2x2), global_load_lds width 16.
enum { EPI_F32 = 0, EPI_GELU = 1, EPI_RES = 2 };

template<int EPI>
__global__ __launch_bounds__(256) void gemm_bt(
    const unsigned short* __restrict__ A,
    const unsigned short* __restrict__ Bt,
    const float* __restrict__ bias,
    const float* __restrict__ resid,
    float* __restrict__ Cf,
    unsigned short* __restrict__ Cb,
    int K, int N)
{
  __shared__ unsigned short As[4096];   // [128][32]
  __shared__ unsigned short Bs[4096];
  const int tid = threadIdx.x;
  const int m0 = blockIdx.x * 128, n0 = blockIdx.y * 128;
  const int lane = tid & 63, wave = tid >> 6;
  const int wr = wave >> 1, wc = wave & 1;
  const int lr = lane & 15, lg = lane >> 4;

  const unsigned short* ga = A  + (size_t)(m0 + (tid >> 2)) * K + (tid & 3) * 8;
  const unsigned short* gb = Bt + (size_t)(n0 + (tid >> 2)) * K + (tid & 3) * 8;
  const size_t rstep = (size_t)64 * K;
  unsigned short* lA = &As[tid * 8];
  unsigned short* lB = &Bs[tid * 8];

  f32x4 acc[4][4];
#pragma unroll
  for (int i = 0; i < 4; i++)
#pragma unroll
    for (int j = 0; j < 4; j++) acc[i][j] = f32x4{0.f, 0.f, 0.f, 0.f};

  for (int kt = 0; kt < K; kt += 32){
    gl_lds16(ga + kt,         lA);
    gl_lds16(ga + kt + rstep, lA + 2048);
    gl_lds16(gb + kt,         lB);
    gl_lds16(gb + kt + rstep, lB + 2048);
    __syncthreads();                       // vmcnt(0) drain -> staged data visible
    bf16x8 af[4], bg[4];
#pragma unroll
    for (int i = 0; i < 4; i++) af[i] = *(const bf16x8*)&As[(wr*64 + i*16 + lr)*32 + lg*8];
#pragma unroll
    for (int j = 0; j < 4; j++) bg[j] = *(const bf16x8*)&Bs[(wc*64 + j*16 + lr)*32 + lg*8];
#pragma unroll
    for (int i = 0; i < 4; i++)
#pragma unroll
      for (int j = 0; j < 4; j++)
        acc[i][j] = __builtin_amdgcn_mfma_f32_16x16x32_bf16(af[i], bg[j], acc[i][j], 0, 0, 0);
    __syncthreads();                       // all reads done before next stage
  }

  // C/D layout (verified): col = lane&15, row = (lane>>4)*4 + reg
#pragma unroll
  for (int i = 0; i < 4; i++){
    const int row = m0 + wr*64 + i*16 + lg*4;
#pragma unroll
    for (int q = 0; q < 4; q++){
      const size_t rbase = (size_t)(row + q) * N;
#pragma unroll
      for (int j = 0; j < 4; j++){
        const int col = n0 + wc*64 + j*16 + lr;
        float v = acc[i][j][q] + bias[col];
        if constexpr (EPI == EPI_F32){
          Cf[rbase + col] = v;
        } else if constexpr (EPI == EPI_RES){
          Cf[rbase + col] = v + resid[rbase + col];
        } else {  // GELU -> bf16:  0.5x(1+tanh(u)) == x*sigmoid(2u) == x/(1+e^(-2u))
          float u = 0.7978845608028654f * (v + 0.044715f * v*v*v);
          float g = v / (1.f + __expf(-2.f * u));
          Cb[rbase + col] = f2b(g);
        }
      }
    }
  }
}

// ---------------- fused attention (f32 VALU; round-1 placeholder, MFMA rewrite later) ----------------
// grid (head, batch); block 256 = 4 waves; K/V staged in LDS (stride 68 pad), 4 q-rows per wave.
__global__ __launch_bounds__(256) void attn(const float* __restrict__ qkv,
                                            unsigned short* __restrict__ o){
  __shared__ float Kl[SEQ * 68];          // 53.6 KB
  __shared__ float Vl[SEQ * 68];          // 53.6 KB
  __shared__ float pl[4][256][4];         // [wave][j][r] 16 KB
  const int hh = blockIdx.x, b = blockIdx.y;
  const int tid = threadIdx.x, wave = tid >> 6, lane = tid & 63;
  const float* base = qkv + (size_t)b * SEQ * QKVN;

  for (int i = tid * 4; i < SEQ * HSZ; i += 1024){
    const int j = i >> 6, d = i & 63;
    *(float4*)&Kl[j*68 + d] = *(const float4*)&base[(size_t)j*QKVN + DIM     + hh*HSZ + d];
    *(float4*)&Vl[j*68 + d] = *(const float4*)&base[(size_t)j*QKVN + 2*DIM   + hh*HSZ + d];
  }
  __syncthreads();

  const float scale = 0.125f;             // 1/sqrt(64)
  const int j0 = lane, j1 = lane + 64, j2 = lane + 128;
  const int j3 = (lane < 5) ? lane + 192 : 196;   // clamp (masked later)

  for (int rg = wave * 4; rg < SEQ; rg += 16){
    float qv[4];
#pragma unroll
    for (int r = 0; r < 4; r++){
      const int row = rg + r;
      qv[r] = (row < SEQ) ? base[(size_t)row*QKVN + hh*HSZ + lane] : 0.f;
    }
    float s_[4][4];
#pragma unroll
    for (int r = 0; r < 4; r++)
#pragma unroll
      for (int t = 0; t < 4; t++) s_[r][t] = 0.f;

#pragma unroll 4
    for (int d0 = 0; d0 < 64; d0 += 4){
      float4 k0 = *(const float4*)&Kl[j0*68 + d0];
      float4 k1 = *(const float4*)&Kl[j1*68 + d0];
      float4 k2 = *(const float4*)&Kl[j2*68 + d0];
      float4 k3 = *(const float4*)&Kl[j3*68 + d0];
#pragma unroll
      for (int r = 0; r < 4; r++){
        float q0 = __shfl(qv[r], d0), q1 = __shfl(qv[r], d0+1);
        float q2 = __shfl(qv[r], d0+2), q3 = __shfl(qv[r], d0+3);
        s_[r][0] += q0*k0.x + q1*k0.y + q2*k0.z + q3*k0.w;
        s_[r][1] += q0*k1.x + q1*k1.y + q2*k1.z + q3*k1.w;
        s_[r][2] += q0*k2.x + q1*k2.y + q2*k2.z + q3*k2.w;
        s_[r][3] += q0*k3.x + q1*k3.y + q2*k3.z + q3*k3.w;
      }
    }

#pragma unroll
    for (int r = 0; r < 4; r++){
      float a0 = s_[r][0]*scale, a1 = s_[r][1]*scale, a2 = s_[r][2]*scale;
      float a3 = (lane < 5) ? s_[r][3]*scale : -1e30f;
      float mx = fmaxf(fmaxf(a0, a1), fmaxf(a2, a3));
#pragma unroll
      for (int off = 32; off; off >>= 1) mx = fmaxf(mx, __shfl_xor(mx, off));
      float e0 = __expf(a0 - mx), e1 = __expf(a1 - mx), e2 = __expf(a2 - mx);
      float e3 = (lane < 5) ? __expf(a3 - mx) : 0.f;
      float sm = e0 + e1 + e2 + e3;
#pragma unroll
      for (int off = 32; off; off >>= 1) sm += __shfl_xor(sm, off);
      float inv = 1.f / sm;
      s_[r][0] = e0*inv; s_[r][1] = e1*inv; s_[r][2] = e2*inv; s_[r][3] = e3*inv;
    }
#pragma unroll
    for (int t = 0; t < 4; t++){
      if (t < 3 || lane < 5){
        float4 w4 = { s_[0][t], s_[1][t], s_[2][t], s_[3][t] };
        *(float4*)&pl[wave][lane + 64*t][0] = w4;
      }
    }

    float oa[4] = {0.f, 0.f, 0.f, 0.f};
    for (int j = 0; j < SEQ; j++){
      float vv = Vl[j*68 + lane];
      float4 p4 = *(const float4*)&pl[wave][j][0];
      oa[0] += p4.x*vv; oa[1] += p4.y*vv; oa[2] += p4.z*vv; oa[3] += p4.w*vv;
    }
#pragma unroll
    for (int r = 0; r < 4; r++){
      const int row = rg + r;
      if (row < SEQ) o[(size_t)(b*SEQ + row)*DIM + hh*HSZ + lane] = f2b(oa[r]);
    }
  }
}

// ---------------- classifier ----------------
__global__ void classifier(const float* __restrict__ h, const float* __restrict__ cw,
                           const float* __restrict__ cb, float* __restrict__ out){
  const int b = blockIdx.x, tid = threadIdx.x, lane = tid & 63, wave = tid >> 6;
  const float* p = h + (size_t)b * SEQ * DIM;    // CLS row
  float s = 0.f;
  for (int c = tid; c < DIM; c += 256) s += p[c] * cw[c];
#pragma unroll
  for (int off = 32; off; off >>= 1) s += __shfl_xor(s, off);
  __shared__ float red[4];
  if (lane == 0) red[wave] = s;
  __syncthreads();
  if (tid == 0) out[b] = red[0] + red[1] + red[2] + red[3] + cb[0];
}

// ---------------- launch ----------------
extern "C" void kernel_launch(void* const* d_in, const int* in_sizes, int n_in,
                              void* d_out, int out_size, void* d_ws, size_t ws_size,
                              hipStream_t stream)
{
  (void)in_sizes; (void)n_in; (void)out_size; (void)ws_size;
  const float* x      = (const float*)d_in[0];
  const float* conv_w = (const float*)d_in[1];
  const float* conv_b = (const float*)d_in[2];
  const float* cls_tk = (const float*)d_in[3];
  const float* pos    = (const float*)d_in[4];
  const float* ln1w   = (const float*)d_in[5];
  const float* ln1b   = (const float*)d_in[6];
  const float* wq     = (const float*)d_in[7];
  const float* bq     = (const float*)d_in[8];
  const float* wk     = (const float*)d_in[9];
  const float* bk     = (const float*)d_in[10];
  const float* wv     = (const float*)d_in[11];
  const float* bv     = (const float*)d_in[12];
  const float* wo     = (const float*)d_in[13];
  const float* bo     = (const float*)d_in[14];
  const float* ln2w   = (const float*)d_in[15];
  const float* ln2b   = (const float*)d_in[16];
  const float* w1     = (const float*)d_in[17];
  const float* b1     = (const float*)d_in[18];
  const float* w2     = (const float*)d_in[19];
  const float* b2     = (const float*)d_in[20];
  const float* cls_w  = (const float*)d_in[21];
  const float* cls_b  = (const float*)d_in[22];
  float* out = (float*)d_out;

  char* wp = (char*)d_ws;
  auto take = [&](size_t bytes) -> void* {
    void* p = (void*)wp;
    wp += (bytes + 255) & ~(size_t)255;
    return p;
  };
  // ~318 MB total
  unsigned short* wtA = (unsigned short*)take((size_t)LAYERS*4*KN*2);        // [l][q,k,v,o][768][768] bf16 (transposed)
  unsigned short* wt1 = (unsigned short*)take((size_t)LAYERS*DIM*HIDDEN*2);  // [l][3072][768]
  unsigned short* wt2 = (unsigned short*)take((size_t)LAYERS*DIM*HIDDEN*2);  // [l][768][3072]
  unsigned short* cwb = (unsigned short*)take((size_t)KN*2);                 // conv_w bf16 (already [N][K])
  float*          bqkv= (float*)take((size_t)LAYERS*QKVN*4);
  unsigned short* pat = (unsigned short*)take((size_t)MPATCH*DIM*2);
  float*          h   = (float*)take((size_t)MPAD*DIM*4);
  unsigned short* hn  = (unsigned short*)take((size_t)MPAD*DIM*2);
  float*          qkv = (float*)take((size_t)MPAD*QKVN*4);
  unsigned short* ob  = (unsigned short*)take((size_t)MPAD*DIM*2);
  unsigned short* mid = (unsigned short*)take((size_t)MPAD*HIDDEN*2);

  // weight prep (redone every call — no persistent state allowed)
  transpose_cast<<<dim3(DIM/32, DIM/32, LAYERS), 256, 0, stream>>>(wq, wtA + 0*KN, DIM, DIM, (size_t)KN, (size_t)4*KN);
  transpose_cast<<<dim3(DIM/32, DIM/32, LAYERS), 256, 0, stream>>>(wk, wtA + 1*KN, DIM, DIM, (size_t)KN, (size_t)4*KN);
  transpose_cast<<<dim3(DIM/32, DIM/32, LAYERS), 256, 0, stream>>>(wv, wtA + 2*KN, DIM, DIM, (size_t)KN, (size_t)4*KN);
  transpose_cast<<<dim3(DIM/32, DIM/32, LAYERS), 256, 0, stream>>>(wo, wtA + 3*KN, DIM, DIM, (size_t)KN, (size_t)4*KN);
  transpose_cast<<<dim3(DIM/32, HIDDEN/32, LAYERS), 256, 0, stream>>>(w1, wt1, DIM, HIDDEN, (size_t)DIM*HIDDEN, (size_t)DIM*HIDDEN);
  transpose_cast<<<dim3(HIDDEN/32, DIM/32, LAYERS), 256, 0, stream>>>(w2, wt2, HIDDEN, DIM, (size_t)DIM*HIDDEN, (size_t)DIM*HIDDEN);
  cast_bf16<<<(KN + 255)/256, 256, 0, stream>>>(conv_w, cwb, KN);
  pack_bias<<<(LAYERS*QKVN + 255)/256, 256, 0, stream>>>(bq, bk, bv, bqkv);

  // patch embed: patchify -> GEMM (conv as matmul) -> assemble (+cls, +pos)
  patchify<<<dim3(MPATCH, 3), 256, 0, stream>>>(x, pat);
  gemm_bt<EPI_F32><<<dim3(MPATCH/128, DIM/128), 256, 0, stream>>>(pat, cwb, conv_b, nullptr, qkv, nullptr, DIM, DIM);
  assemble<<<dim3(MREAL, 3), 256, 0, stream>>>(qkv, cls_tk, pos, h);

  for (int l = 0; l < LAYERS; ++l){
    ln_bf16<<<MREAL/4, 256, 0, stream>>>(h, ln1w + l*DIM, ln1b + l*DIM, hn, MREAL);
    gemm_bt<EPI_F32><<<dim3(MPAD/128, QKVN/128), 256, 0, stream>>>(
        hn, wtA + (size_t)l*4*KN, bqkv + l*QKVN, nullptr, qkv, nullptr, DIM, QKVN);
    attn<<<dim3(NHEAD, BATCH), 256, 0, stream>>>(qkv, ob);
    gemm_bt<EPI_RES><<<dim3(MPAD/128, DIM/128), 256, 0, stream>>>(
        ob, wtA + ((size_t)l*4 + 3)*KN, bo + l*DIM, h, h, nullptr, DIM, DIM);
    ln_bf16<<<MREAL/4, 256, 0, stream>>>(h, ln2w + l*DIM, ln2b + l*DIM, hn, MREAL);
    gemm_bt<EPI_GELU><<<dim3(MPAD/128, HIDDEN/128), 256, 0, stream>>>(
        hn, wt1 + (size_t)l*DIM*HIDDEN, b1 + l*HIDDEN, nullptr, nullptr, mid, DIM, HIDDEN);
    gemm_bt<EPI_RES><<<dim3(MPAD/128, DIM/128), 256, 0, stream>>>(
        mid, wt2 + (size_t)l*DIM*HIDDEN, b2 + l*DIM, h, h, nullptr, HIDDEN, DIM);
  }

  classifier<<<BATCH, 256, 0, stream>>>(h, cls_w, cls_b, out);
}

// Round 5
// 3904.841 us; speedup vs baseline: 1.7123x; 1.7123x over previous
//
#include <hip/hip_runtime.h>

#define AS1 __attribute__((address_space(1)))
#define AS3 __attribute__((address_space(3)))

using f32x4  = __attribute__((ext_vector_type(4))) float;
using bf16x8 = __attribute__((ext_vector_type(8))) __bf16;

// ---- ViT-B/16 constants (B=32) ----
#define LAYERS 12
#define DIM    768
#define HIDDEN 3072
#define NHEAD  12
#define HSZ    64
#define BATCH  32
#define NPATCH 196
#define SEQ    197
#define MREAL  (BATCH*SEQ)      // 6304
#define MPAD   6400             // 50*128
#define MPATCH (BATCH*NPATCH)   // 6272 = 49*128
#define QKVN   (3*DIM)          // 2304
#define KN     (DIM*DIM)

static __device__ __forceinline__ unsigned short f2b(float f){
  unsigned int u = __float_as_uint(f);
  u = (u + 0x7FFFu + ((u >> 16) & 1u)) >> 16;   // RNE to bf16
  return (unsigned short)u;
}

static __device__ __forceinline__ bf16x8 u4_to_b8(uint4 u){
  union { uint4 a; bf16x8 b; } x; x.a = u; return x.b;
}

static __device__ __forceinline__ void gl_lds16(const unsigned short* g, unsigned short* l){
  __builtin_amdgcn_global_load_lds((AS1 void*)g, (AS3 void*)l, 16, 0, 0);
}

// ---------------- weight prep ----------------
__global__ void transpose_cast(const float* __restrict__ src, unsigned short* __restrict__ dst,
                               int K, int N, size_t sls, size_t dls){
  __shared__ float tile[32][33];
  const int l  = blockIdx.z;
  const int k0 = blockIdx.x * 32;
  const int n0 = blockIdx.y * 32;
  const float* s = src + (size_t)l * sls;
  unsigned short* d = dst + (size_t)l * dls;
  const int tx = threadIdx.x & 31, ty = threadIdx.x >> 5;   // 32 x 8
#pragma unroll
  for (int r = 0; r < 32; r += 8)
    tile[ty + r][tx] = s[(size_t)(k0 + ty + r) * N + n0 + tx];
  __syncthreads();
#pragma unroll
  for (int r = 0; r < 32; r += 8)
    d[(size_t)(n0 + ty + r) * K + k0 + tx] = f2b(tile[tx][ty + r]);
}

__global__ void cast_bf16(const float* __restrict__ s, unsigned short* __restrict__ d, int n){
  int i = blockIdx.x * 256 + threadIdx.x;
  if (i < n) d[i] = f2b(s[i]);
}

__global__ void pack_bias(const float* __restrict__ bq, const float* __restrict__ bk,
                          const float* __restrict__ bv, float* __restrict__ dst){
  int i = blockIdx.x * 256 + threadIdx.x;
  if (i >= LAYERS * QKVN) return;
  int l = i / QKVN, c = i % QKVN;
  float v = (c < DIM) ? bq[l*DIM + c] : (c < 2*DIM) ? bk[l*DIM + c - DIM] : bv[l*DIM + c - 2*DIM];
  dst[i] = v;
}

// ---------------- patch embed ----------------
__global__ void patchify(const float* __restrict__ x, unsigned short* __restrict__ pat){
  const int row = blockIdx.x;                       // b*196+p
  const int cc  = blockIdx.y * 256 + threadIdx.x;   // 0..767
  const int b = row / NPATCH, p = row % NPATCH;
  const int c = cc >> 8, rem = cc & 255, ii = rem >> 4, jj = rem & 15;
  const int pr = p / 14, pc = p % 14;
  float v = x[(((size_t)(b*3 + c) * 224) + pr*16 + ii) * 224 + pc*16 + jj];
  pat[(size_t)row * DIM + cc] = f2b(v);
}

__global__ void assemble(const float* __restrict__ yq, const float* __restrict__ cls,
                         const float* __restrict__ pos, float* __restrict__ h){
  const int row = blockIdx.x;                       // 0..6303
  const int d   = blockIdx.y * 256 + threadIdx.x;
  const int b = row / SEQ, p = row % SEQ;
  float v = (p == 0) ? cls[d] : yq[(size_t)(b*NPATCH + p - 1) * DIM + d];
  h[(size_t)row * DIM + d] = v + pos[p*DIM + d];
}

// ---------------- layernorm (f32 in, bf16 out) ----------------
__global__ __launch_bounds__(256) void ln_bf16(const float* __restrict__ h,
                const float* __restrict__ w, const float* __restrict__ b,
                unsigned short* __restrict__ out, int nrows){
  const int wave = threadIdx.x >> 6, lane = threadIdx.x & 63;
  const int row = blockIdx.x * 4 + wave;
  if (row >= nrows) return;
  const float* p = h + (size_t)row * DIM;
  float4 v[3]; float s = 0.f, ss = 0.f;
#pragma unroll
  for (int t = 0; t < 3; t++){
    v[t] = *(const float4*)&p[lane*4 + t*256];
    s  += v[t].x + v[t].y + v[t].z + v[t].w;
    ss += v[t].x*v[t].x + v[t].y*v[t].y + v[t].z*v[t].z + v[t].w*v[t].w;
  }
#pragma unroll
  for (int off = 32; off; off >>= 1){ s += __shfl_xor(s, off); ss += __shfl_xor(ss, off); }
  const float mean = s * (1.f/DIM);
  const float inv  = rsqrtf(ss * (1.f/DIM) - mean*mean + 1e-5f);
#pragma unroll
  for (int t = 0; t < 3; t++){
    const int c = lane*4 + t*256;
    float4 wv = *(const float4*)&w[c];
    float4 bv = *(const float4*)&b[c];
    ushort4 o;
    o.x = f2b((v[t].x - mean)*inv*wv.x + bv.x);
    o.y = f2b((v[t].y - mean)*inv*wv.y + bv.y);
    o.z = f2b((v[t].z - mean)*inv*wv.z + bv.z);
    o.w = f2b((v[t].w - mean)*inv*wv.w + bv.w);
    *(ushort4*)&out[(size_t)row * DIM + c] = o;
  }
}

// ---------------- GEMM: C[M,N] = A[M,K](bf16) @ Bt[N,K](bf16)^T + bias (+epilogue) ----------------
enum { EPI_F32 = 0, EPI_GELU = 1, EPI_RES = 2 };

template<int EPI>
__global__ __launch_bounds__(256) void gemm_bt(
    const unsigned short* __restrict__ A,
    const unsigned short* __restrict__ Bt,
    const float* __restrict__ bias,
    const float* __restrict__ resid,
    float* __restrict__ Cf,
    unsigned short* __restrict__ Cb,
    int K, int N)
{
  __shared__ unsigned short As[4096];   // [128][32]
  __shared__ unsigned short Bs[4096];
  const int tid = threadIdx.x;
  const int m0 = blockIdx.x * 128, n0 = blockIdx.y * 128;
  const int lane = tid & 63, wave = tid >> 6;
  const int wr = wave >> 1, wc = wave & 1;
  const int lr = lane & 15, lg = lane >> 4;

  const unsigned short* ga = A  + (size_t)(m0 + (tid >> 2)) * K + (tid & 3) * 8;
  const unsigned short* gb = Bt + (size_t)(n0 + (tid >> 2)) * K + (tid & 3) * 8;
  const size_t rstep = (size_t)64 * K;
  unsigned short* lA = &As[tid * 8];
  unsigned short* lB = &Bs[tid * 8];

  f32x4 acc[4][4];
#pragma unroll
  for (int i = 0; i < 4; i++)
#pragma unroll
    for (int j = 0; j < 4; j++) acc[i][j] = f32x4{0.f, 0.f, 0.f, 0.f};

  for (int kt = 0; kt < K; kt += 32){
    gl_lds16(ga + kt,         lA);
    gl_lds16(ga + kt + rstep, lA + 2048);
    gl_lds16(gb + kt,         lB);
    gl_lds16(gb + kt + rstep, lB + 2048);
    __syncthreads();
    bf16x8 af[4], bg[4];
#pragma unroll
    for (int i = 0; i < 4; i++) af[i] = *(const bf16x8*)&As[(wr*64 + i*16 + lr)*32 + lg*8];
#pragma unroll
    for (int j = 0; j < 4; j++) bg[j] = *(const bf16x8*)&Bs[(wc*64 + j*16 + lr)*32 + lg*8];
#pragma unroll
    for (int i = 0; i < 4; i++)
#pragma unroll
      for (int j = 0; j < 4; j++)
        acc[i][j] = __builtin_amdgcn_mfma_f32_16x16x32_bf16(af[i], bg[j], acc[i][j], 0, 0, 0);
    __syncthreads();
  }

  // C/D layout: col = lane&15, row = (lane>>4)*4 + reg
#pragma unroll
  for (int i = 0; i < 4; i++){
    const int row = m0 + wr*64 + i*16 + lg*4;
#pragma unroll
    for (int q = 0; q < 4; q++){
      const size_t rbase = (size_t)(row + q) * N;
#pragma unroll
      for (int j = 0; j < 4; j++){
        const int col = n0 + wc*64 + j*16 + lr;
        float v = acc[i][j][q] + bias[col];
        if constexpr (EPI == EPI_F32){
          Cf[rbase + col] = v;
        } else if constexpr (EPI == EPI_RES){
          Cf[rbase + col] = v + resid[rbase + col];
        } else {  // GELU -> bf16:  0.5x(1+tanh(u)) == x/(1+e^(-2u))
          float u = 0.7978845608028654f * (v + 0.044715f * v*v*v);
          float g = v / (1.f + __expf(-2.f * u));
          Cb[rbase + col] = f2b(g);
        }
      }
    }
  }
}

// ---------------- MFMA fused attention ----------------
// grid (head, batch); 512 threads = 8 waves; one (b,h) per block.
// LDS: Ks [208][64] bf16 XOR-swizzled; Vt [64][(256)] stride-512B swizzled (V transposed);
//      Ps per-wave 14 tiles of 512B, tile layout (row&3)*128+(row>>2)*32+2c.
__global__ __launch_bounds__(512) void attn_mfma(const float* __restrict__ qkv,
                                                 unsigned short* __restrict__ ob){
  __shared__ unsigned short Ks[208*64];        // 26.0 KB
  __shared__ unsigned short Vt[64*256];        // 32 KB
  __shared__ unsigned short Ps[8*14*256];      // 56 KB
  const int hh = blockIdx.x, b = blockIdx.y;
  const int tid = threadIdx.x, w = tid >> 6, lane = tid & 63;
  const int c = lane & 15, g = lane >> 4;
  const float* base = qkv + (size_t)b * SEQ * QKVN;
  char* KsB = (char*)Ks;
  char* VtB = (char*)Vt;
  char* PsB = (char*)(Ps + w * 3584);          // 7168 B per wave

  // zero the whole Ps region (cols >=197 and tile 13 must stay zero)
  for (int i = tid; i < 3584; i += 512) ((uint4*)Ps)[i] = make_uint4(0,0,0,0);

  // stage K rows 0..207 (zero-fill >=197): bf16, byte = r*128 + ((2*d0) ^ ((r&7)<<4))
  for (int cc = tid; cc < 208*8; cc += 512){
    const int r = cc >> 3, d0 = (cc & 7) * 8;
    uint4 u = make_uint4(0,0,0,0);
    if (r < SEQ){
      const float* p = base + (size_t)r*QKVN + DIM + hh*HSZ + d0;
      float4 f0 = *(const float4*)p;
      float4 f1 = *(const float4*)(p + 4);
      u.x = f2b(f0.x) | ((unsigned)f2b(f0.y) << 16);
      u.y = f2b(f0.z) | ((unsigned)f2b(f0.w) << 16);
      u.z = f2b(f1.x) | ((unsigned)f2b(f1.y) << 16);
      u.w = f2b(f1.z) | ((unsigned)f2b(f1.w) << 16);
    }
    *(uint4*)(KsB + r*128 + ((d0*2) ^ ((r & 7) << 4))) = u;
  }
  // stage V transposed, k 0..223 (zero-fill >=197): byte = d*512 + ((2k) ^ ((d&7)<<4))
  for (int cc = tid; cc < 224*16; cc += 512){
    const int k = cc >> 4, d0 = (cc & 15) * 4;
    float4 f = make_float4(0.f, 0.f, 0.f, 0.f);
    if (k < SEQ) f = *(const float4*)(base + (size_t)k*QKVN + 2*DIM + hh*HSZ + d0);
    unsigned short h0 = f2b(f.x), h1 = f2b(f.y), h2 = f2b(f.z), h3 = f2b(f.w);
    *(unsigned short*)(VtB + (d0+0)*512 + ((2*k) ^ (((d0+0) & 7) << 4))) = h0;
    *(unsigned short*)(VtB + (d0+1)*512 + ((2*k) ^ (((d0+1) & 7) << 4))) = h1;
    *(unsigned short*)(VtB + (d0+2)*512 + ((2*k) ^ (((d0+2) & 7) << 4))) = h2;
    *(unsigned short*)(VtB + (d0+3)*512 + ((2*k) ^ (((d0+3) & 7) << 4))) = h3;
  }
  __syncthreads();

  const float scale = 0.125f;                  // 1/sqrt(64), pow2 -> exact in bf16
  for (int qt = w; qt < 13; qt += 8){
    // Q fragments from global f32 (scale folded into cast)
    bf16x8 qf[2];
    {
      const float* qp = base + (size_t)(qt*16 + c)*QKVN + hh*HSZ + g*8;
#pragma unroll
      for (int s = 0; s < 2; s++){
        float4 f0 = *(const float4*)(qp + 32*s);
        float4 f1 = *(const float4*)(qp + 32*s + 4);
        uint4 u;
        u.x = f2b(f0.x*scale) | ((unsigned)f2b(f0.y*scale) << 16);
        u.y = f2b(f0.z*scale) | ((unsigned)f2b(f0.w*scale) << 16);
        u.z = f2b(f1.x*scale) | ((unsigned)f2b(f1.y*scale) << 16);
        u.w = f2b(f1.z*scale) | ((unsigned)f2b(f1.w*scale) << 16);
        qf[s] = u4_to_b8(u);
      }
    }
    // QK^T: acc[j] = 16x16 tile vs K rows j*16..+15
    f32x4 acc[13];
#pragma unroll
    for (int j = 0; j < 13; j++) acc[j] = f32x4{0.f, 0.f, 0.f, 0.f};
#pragma unroll
    for (int j = 0; j < 13; j++){
#pragma unroll
      for (int s = 0; s < 2; s++){
        const int kr = j*16 + c;
        bf16x8 kf = *(const bf16x8*)(KsB + kr*128 + ((16*g + 64*s) ^ ((kr & 7) << 4)));
        acc[j] = __builtin_amdgcn_mfma_f32_16x16x32_bf16(qf[s], kf, acc[j], 0, 0, 0);
      }
    }
    // mask cols 197..207 (tile 12, c>=5)
    if (c >= 5){ acc[12][0] = -1e30f; acc[12][1] = -1e30f; acc[12][2] = -1e30f; acc[12][3] = -1e30f; }
    // softmax per row (rows live in regs r, cols across lanes of 16-group + 13 tiles)
    float inv[4];
#pragma unroll
    for (int r = 0; r < 4; r++){
      float m = acc[0][r];
#pragma unroll
      for (int j = 1; j < 13; j++) m = fmaxf(m, acc[j][r]);
      m = fmaxf(m, __shfl_xor(m, 1)); m = fmaxf(m, __shfl_xor(m, 2));
      m = fmaxf(m, __shfl_xor(m, 4)); m = fmaxf(m, __shfl_xor(m, 8));
      float s = 0.f;
#pragma unroll
      for (int j = 0; j < 13; j++){ float e = __expf(acc[j][r] - m); acc[j][r] = e; s += e; }
      s += __shfl_xor(s, 1); s += __shfl_xor(s, 2); s += __shfl_xor(s, 4); s += __shfl_xor(s, 8);
      inv[r] = 1.f / s;
    }
    // write P (bf16) to per-wave LDS tiles; masked cols stay zero from init
#pragma unroll
    for (int j = 0; j < 13; j++){
#pragma unroll
      for (int r = 0; r < 4; r++){
        if (j < 12 || c < 5){
          const int row = g*4 + r;
          *(unsigned short*)(PsB + j*512 + (row & 3)*128 + (row >> 2)*32 + 2*c) = f2b(acc[j][r]);
        }
      }
    }
    asm volatile("s_waitcnt lgkmcnt(0)" ::: "memory");   // cross-lane LDS dep within wave
    __builtin_amdgcn_sched_barrier(0);
    // PV: O[16][64] = P[16][224] @ V[224][64]
    f32x4 oacc[4];
#pragma unroll
    for (int dt = 0; dt < 4; dt++) oacc[dt] = f32x4{0.f, 0.f, 0.f, 0.f};
#pragma unroll
    for (int ks = 0; ks < 7; ks++){
      const int j = 2*ks + (g >> 1);
      bf16x8 pf = *(const bf16x8*)(PsB + j*512 + (c & 3)*128 + (c >> 2)*32 + 16*(g & 1));
#pragma unroll
      for (int dt = 0; dt < 4; dt++){
        const int d = dt*16 + c;
        bf16x8 vf = *(const bf16x8*)(VtB + d*512 + ((16*g + 64*ks) ^ ((d & 7) << 4)));
        oacc[dt] = __builtin_amdgcn_mfma_f32_16x16x32_bf16(pf, vf, oacc[dt], 0, 0, 0);
      }
    }
    // store O (bf16), rescaled by 1/sum
#pragma unroll
    for (int dt = 0; dt < 4; dt++){
#pragma unroll
      for (int r = 0; r < 4; r++){
        const int rt = qt*16 + g*4 + r;
        if (rt < SEQ)
          ob[(size_t)(b*SEQ + rt)*DIM + hh*HSZ + dt*16 + c] = f2b(oacc[dt][r] * inv[r]);
      }
    }
  }
}

// ---------------- classifier ----------------
__global__ void classifier(const float* __restrict__ h, const float* __restrict__ cw,
                           const float* __restrict__ cb, float* __restrict__ out){
  const int b = blockIdx.x, tid = threadIdx.x, lane = tid & 63, wave = tid >> 6;
  const float* p = h + (size_t)b * SEQ * DIM;    // CLS row
  float s = 0.f;
  for (int c = tid; c < DIM; c += 256) s += p[c] * cw[c];
#pragma unroll
  for (int off = 32; off; off >>= 1) s += __shfl_xor(s, off);
  __shared__ float red[4];
  if (lane == 0) red[wave] = s;
  __syncthreads();
  if (tid == 0) out[b] = red[0] + red[1] + red[2] + red[3] + cb[0];
}

// ---------------- launch ----------------
extern "C" void kernel_launch(void* const* d_in, const int* in_sizes, int n_in,
                              void* d_out, int out_size, void* d_ws, size_t ws_size,
                              hipStream_t stream)
{
  (void)in_sizes; (void)n_in; (void)out_size; (void)ws_size;
  const float* x      = (const float*)d_in[0];
  const float* conv_w = (const float*)d_in[1];
  const float* conv_b = (const float*)d_in[2];
  const float* cls_tk = (const float*)d_in[3];
  const float* pos    = (const float*)d_in[4];
  const float* ln1w   = (const float*)d_in[5];
  const float* ln1b   = (const float*)d_in[6];
  const float* wq     = (const float*)d_in[7];
  const float* bq     = (const float*)d_in[8];
  const float* wk     = (const float*)d_in[9];
  const float* bk     = (const float*)d_in[10];
  const float* wv     = (const float*)d_in[11];
  const float* bv     = (const float*)d_in[12];
  const float* wo     = (const float*)d_in[13];
  const float* bo     = (const float*)d_in[14];
  const float* ln2w   = (const float*)d_in[15];
  const float* ln2b   = (const float*)d_in[16];
  const float* w1     = (const float*)d_in[17];
  const float* b1     = (const float*)d_in[18];
  const float* w2     = (const float*)d_in[19];
  const float* b2     = (const float*)d_in[20];
  const float* cls_w  = (const float*)d_in[21];
  const float* cls_b  = (const float*)d_in[22];
  float* out = (float*)d_out;

  char* wp = (char*)d_ws;
  auto take = [&](size_t bytes) -> void* {
    void* p = (void*)wp;
    wp += (bytes + 255) & ~(size_t)255;
    return p;
  };
  unsigned short* wtA = (unsigned short*)take((size_t)LAYERS*4*KN*2);
  unsigned short* wt1 = (unsigned short*)take((size_t)LAYERS*DIM*HIDDEN*2);
  unsigned short* wt2 = (unsigned short*)take((size_t)LAYERS*DIM*HIDDEN*2);
  unsigned short* cwb = (unsigned short*)take((size_t)KN*2);
  float*          bqkv= (float*)take((size_t)LAYERS*QKVN*4);
  unsigned short* pat = (unsigned short*)take((size_t)MPATCH*DIM*2);
  float*          h   = (float*)take((size_t)MPAD*DIM*4);
  unsigned short* hn  = (unsigned short*)take((size_t)MPAD*DIM*2);
  float*          qkv = (float*)take((size_t)MPAD*QKVN*4);
  unsigned short* ob  = (unsigned short*)take((size_t)MPAD*DIM*2);
  unsigned short* mid = (unsigned short*)take((size_t)MPAD*HIDDEN*2);

  transpose_cast<<<dim3(DIM/32, DIM/32, LAYERS), 256, 0, stream>>>(wq, wtA + 0*KN, DIM, DIM, (size_t)KN, (size_t)4*KN);
  transpose_cast<<<dim3(DIM/32, DIM/32, LAYERS), 256, 0, stream>>>(wk, wtA + 1*KN, DIM, DIM, (size_t)KN, (size_t)4*KN);
  transpose_cast<<<dim3(DIM/32, DIM/32, LAYERS), 256, 0, stream>>>(wv, wtA + 2*KN, DIM, DIM, (size_t)KN, (size_t)4*KN);
  transpose_cast<<<dim3(DIM/32, DIM/32, LAYERS), 256, 0, stream>>>(wo, wtA + 3*KN, DIM, DIM, (size_t)KN, (size_t)4*KN);
  transpose_cast<<<dim3(DIM/32, HIDDEN/32, LAYERS), 256, 0, stream>>>(w1, wt1, DIM, HIDDEN, (size_t)DIM*HIDDEN, (size_t)DIM*HIDDEN);
  transpose_cast<<<dim3(HIDDEN/32, DIM/32, LAYERS), 256, 0, stream>>>(w2, wt2, HIDDEN, DIM, (size_t)DIM*HIDDEN, (size_t)DIM*HIDDEN);
  cast_bf16<<<(KN + 255)/256, 256, 0, stream>>>(conv_w, cwb, KN);
  pack_bias<<<(LAYERS*QKVN + 255)/256, 256, 0, stream>>>(bq, bk, bv, bqkv);

  patchify<<<dim3(MPATCH, 3), 256, 0, stream>>>(x, pat);
  gemm_bt<EPI_F32><<<dim3(MPATCH/128, DIM/128), 256, 0, stream>>>(pat, cwb, conv_b, nullptr, qkv, nullptr, DIM, DIM);
  assemble<<<dim3(MREAL, 3), 256, 0, stream>>>(qkv, cls_tk, pos, h);

  for (int l = 0; l < LAYERS; ++l){
    ln_bf16<<<MREAL/4, 256, 0, stream>>>(h, ln1w + l*DIM, ln1b + l*DIM, hn, MREAL);
    gemm_bt<EPI_F32><<<dim3(MPAD/128, QKVN/128), 256, 0, stream>>>(
        hn, wtA + (size_t)l*4*KN, bqkv + l*QKVN, nullptr, qkv, nullptr, DIM, QKVN);
    attn_mfma<<<dim3(NHEAD, BATCH), 512, 0, stream>>>(qkv, ob);
    gemm_bt<EPI_RES><<<dim3(MPAD/128, DIM/128), 256, 0, stream>>>(
        ob, wtA + ((size_t)l*4 + 3)*KN, bo + l*DIM, h, h, nullptr, DIM, DIM);
    ln_bf16<<<MREAL/4, 256, 0, stream>>>(h, ln2w + l*DIM, ln2b + l*DIM, hn, MREAL);
    gemm_bt<EPI_GELU><<<dim3(MPAD/128, HIDDEN/128), 256, 0, stream>>>(
        hn, wt1 + (size_t)l*DIM*HIDDEN, b1 + l*HIDDEN, nullptr, nullptr, mid, DIM, HIDDEN);
    gemm_bt<EPI_RES><<<dim3(MPAD/128, DIM/128), 256, 0, stream>>>(
        mid, wt2 + (size_t)l*DIM*HIDDEN, b2 + l*DIM, h, h, nullptr, HIDDEN, DIM);
  }

  classifier<<<BATCH, 256, 0, stream>>>(h, cls_w, cls_b, out);
}

// Round 7
// 3289.806 us; speedup vs baseline: 2.0325x; 1.1870x over previous
//
#include <hip/hip_runtime.h>

#define AS1 __attribute__((address_space(1)))
#define AS3 __attribute__((address_space(3)))

using f32x4  = __attribute__((ext_vector_type(4))) float;
using bf16x8 = __attribute__((ext_vector_type(8))) __bf16;

// ---- ViT-B/16 constants (B=32) ----
#define LAYERS 12
#define DIM    768
#define HIDDEN 3072
#define NHEAD  12
#define HSZ    64
#define BATCH  32
#define NPATCH 196
#define SEQ    197
#define MREAL  (BATCH*SEQ)      // 6304
#define MPAD   6400             // 50*128
#define MPATCH (BATCH*NPATCH)   // 6272 = 49*128
#define QKVN   (3*DIM)          // 2304
#define KN     (DIM*DIM)

static __device__ __forceinline__ unsigned short f2b(float f){
  unsigned int u = __float_as_uint(f);
  u = (u + 0x7FFFu + ((u >> 16) & 1u)) >> 16;   // RNE to bf16
  return (unsigned short)u;
}

static __device__ __forceinline__ void gl_lds16(const unsigned short* g, unsigned short* l){
  __builtin_amdgcn_global_load_lds((AS1 void*)g, (AS3 void*)l, 16, 0, 0);
}

// ---------------- weight prep ----------------
__global__ void transpose_cast(const float* __restrict__ src, unsigned short* __restrict__ dst,
                               int K, int N, size_t sls, size_t dls){
  __shared__ float tile[32][33];
  const int l  = blockIdx.z;
  const int k0 = blockIdx.x * 32;
  const int n0 = blockIdx.y * 32;
  const float* s = src + (size_t)l * sls;
  unsigned short* d = dst + (size_t)l * dls;
  const int tx = threadIdx.x & 31, ty = threadIdx.x >> 5;   // 32 x 8
#pragma unroll
  for (int r = 0; r < 32; r += 8)
    tile[ty + r][tx] = s[(size_t)(k0 + ty + r) * N + n0 + tx];
  __syncthreads();
#pragma unroll
  for (int r = 0; r < 32; r += 8)
    d[(size_t)(n0 + ty + r) * K + k0 + tx] = f2b(tile[tx][ty + r]);
}

__global__ void cast_bf16(const float* __restrict__ s, unsigned short* __restrict__ d, int n){
  int i = blockIdx.x * 256 + threadIdx.x;
  if (i < n) d[i] = f2b(s[i]);
}

__global__ void pack_bias(const float* __restrict__ bq, const float* __restrict__ bk,
                          const float* __restrict__ bv, float* __restrict__ dst){
  int i = blockIdx.x * 256 + threadIdx.x;
  if (i >= LAYERS * QKVN) return;
  int l = i / QKVN, c = i % QKVN;
  float v = (c < DIM) ? bq[l*DIM + c] : (c < 2*DIM) ? bk[l*DIM + c - DIM] : bv[l*DIM + c - 2*DIM];
  dst[i] = v;
}

// ---------------- patch embed ----------------
__global__ void patchify(const float* __restrict__ x, unsigned short* __restrict__ pat){
  const int row = blockIdx.x;                       // b*196+p
  const int cc  = blockIdx.y * 256 + threadIdx.x;   // 0..767
  const int b = row / NPATCH, p = row % NPATCH;
  const int c = cc >> 8, rem = cc & 255, ii = rem >> 4, jj = rem & 15;
  const int pr = p / 14, pc = p % 14;
  float v = x[(((size_t)(b*3 + c) * 224) + pr*16 + ii) * 224 + pc*16 + jj];
  pat[(size_t)row * DIM + cc] = f2b(v);
}

__global__ void assemble(const float* __restrict__ yq, const float* __restrict__ cls,
                         const float* __restrict__ pos, float* __restrict__ h){
  const int row = blockIdx.x;                       // 0..6303
  const int d   = blockIdx.y * 256 + threadIdx.x;
  const int b = row / SEQ, p = row % SEQ;
  float v = (p == 0) ? cls[d] : yq[(size_t)(b*NPATCH + p - 1) * DIM + d];
  h[(size_t)row * DIM + d] = v + pos[p*DIM + d];
}

// ---------------- layernorm (f32 in, bf16 out) ----------------
__global__ __launch_bounds__(256) void ln_bf16(const float* __restrict__ h,
                const float* __restrict__ w, const float* __restrict__ b,
                unsigned short* __restrict__ out, int nrows){
  const int wave = threadIdx.x >> 6, lane = threadIdx.x & 63;
  const int row = blockIdx.x * 4 + wave;
  if (row >= nrows) return;
  const float* p = h + (size_t)row * DIM;
  float4 v[3]; float s = 0.f, ss = 0.f;
#pragma unroll
  for (int t = 0; t < 3; t++){
    v[t] = *(const float4*)&p[lane*4 + t*256];
    s  += v[t].x + v[t].y + v[t].z + v[t].w;
    ss += v[t].x*v[t].x + v[t].y*v[t].y + v[t].z*v[t].z + v[t].w*v[t].w;
  }
#pragma unroll
  for (int off = 32; off; off >>= 1){ s += __shfl_xor(s, off); ss += __shfl_xor(ss, off); }
  const float mean = s * (1.f/DIM);
  const float inv  = rsqrtf(ss * (1.f/DIM) - mean*mean + 1e-5f);
#pragma unroll
  for (int t = 0; t < 3; t++){
    const int c = lane*4 + t*256;
    float4 wv = *(const float4*)&w[c];
    float4 bv = *(const float4*)&b[c];
    ushort4 o;
    o.x = f2b((v[t].x - mean)*inv*wv.x + bv.x);
    o.y = f2b((v[t].y - mean)*inv*wv.y + bv.y);
    o.z = f2b((v[t].z - mean)*inv*wv.z + bv.z);
    o.w = f2b((v[t].w - mean)*inv*wv.w + bv.w);
    *(ushort4*)&out[(size_t)row * DIM + c] = o;
  }
}

// ---------------- GEMM: C[M,N] = A[M,K](bf16) @ Bt[N,K](bf16)^T + bias (+epilogue) ----------------
// 2-phase double-buffered (T3 minimum recipe), chunk-swizzled LDS (2-way floor),
// grid x = n (fastest) for A-panel L2 reuse. BN in {64,128}.
enum { EPI_F32 = 0, EPI_GELU = 1, EPI_RES = 2, EPI_B16 = 3 };

template<int EPI, int BN>
__global__ __launch_bounds__(256) void gemm_bt(
    const unsigned short* __restrict__ A,
    const unsigned short* __restrict__ Bt,
    const float* __restrict__ bias,
    const float* __restrict__ resid,
    float* __restrict__ Cf,
    unsigned short* __restrict__ Cb,
    int K, int N)
{
  constexpr int NJ = BN / 32;              // n-tiles per wave
  __shared__ unsigned short As[2][4096];   // [128][32] per buffer
  __shared__ unsigned short Bs[2][BN*32];
  const int tid = threadIdx.x;
  const int n0 = blockIdx.x * BN, m0 = blockIdx.y * 128;
  const int lane = tid & 63, wave = tid >> 6;
  const int wr = wave >> 1, wc = wave & 1;
  const int lr = lane & 15, lg = lane >> 4;

  // staging: thread tid -> LDS row tid>>2, chunk tid&3 (linear dest, required by global_load_lds).
  // source carries the swizzle: chunk' = (tid&3) ^ ((row>>1)&3), row = tid>>2  => (tid>>3)&3.
  const int schunk = (tid & 3) ^ ((tid >> 3) & 3);
  const unsigned short* ga = A  + (size_t)(m0 + (tid >> 2)) * K + schunk * 8;
  const unsigned short* gb = Bt + (size_t)(n0 + (tid >> 2)) * K + schunk * 8;
  const size_t rstep = (size_t)64 * K;

  f32x4 acc[4][NJ];
#pragma unroll
  for (int i = 0; i < 4; i++)
#pragma unroll
    for (int j = 0; j < NJ; j++) acc[i][j] = f32x4{0.f, 0.f, 0.f, 0.f};

  auto stage = [&](int bf, int kt){
    gl_lds16(ga + kt,         &As[bf][tid*8]);
    gl_lds16(ga + kt + rstep, &As[bf][2048 + tid*8]);
    gl_lds16(gb + kt,         &Bs[bf][tid*8]);
    if constexpr (BN == 128) gl_lds16(gb + kt + rstep, &Bs[bf][2048 + tid*8]);
  };
  // read-side swizzle: chunk = lg ^ ((row>>1)&3); row offsets are multiples of 16 so it's lg ^ ((lr>>1)&3)
  const int rchunk = (lg ^ ((lr >> 1) & 3)) * 8;
  auto compute = [&](int bf){
    bf16x8 af[4], bg[NJ];
#pragma unroll
    for (int i = 0; i < 4; i++)
      af[i] = *(const bf16x8*)&As[bf][(wr*64 + i*16 + lr)*32 + rchunk];
#pragma unroll
    for (int j = 0; j < NJ; j++)
      bg[j] = *(const bf16x8*)&Bs[bf][(wc*(BN/2) + j*16 + lr)*32 + rchunk];
#pragma unroll
    for (int i = 0; i < 4; i++)
#pragma unroll
      for (int j = 0; j < NJ; j++)
        acc[i][j] = __builtin_amdgcn_mfma_f32_16x16x32_bf16(af[i], bg[j], acc[i][j], 0, 0, 0);
  };

  stage(0, 0);
  __syncthreads();                        // vmcnt(0) drain: buf0 ready
  int cur = 0;
  for (int kt = 32; kt < K; kt += 32){
    stage(cur ^ 1, kt);                   // prefetch next tile (overlaps compute below)
    compute(cur);
    __syncthreads();                      // drains lgkm (reads done) + vmcnt (next buf ready)
    cur ^= 1;
  }
  compute(cur);

  // C/D layout: col = lane&15, row = (lane>>4)*4 + reg
#pragma unroll
  for (int i = 0; i < 4; i++){
    const int row = m0 + wr*64 + i*16 + lg*4;
#pragma unroll
    for (int q = 0; q < 4; q++){
      const size_t rbase = (size_t)(row + q) * N;
#pragma unroll
      for (int j = 0; j < NJ; j++){
        const int col = n0 + wc*(BN/2) + j*16 + lr;
        float v = acc[i][j][q] + bias[col];
        if constexpr (EPI == EPI_F32){
          Cf[rbase + col] = v;
        } else if constexpr (EPI == EPI_RES){
          Cf[rbase + col] = v + resid[rbase + col];
        } else if constexpr (EPI == EPI_B16){
          Cb[rbase + col] = f2b(v);
        } else {  // GELU -> bf16:  0.5x(1+tanh(u)) == x/(1+e^(-2u))
          float u = 0.7978845608028654f * (v + 0.044715f * v*v*v);
          float g = v / (1.f + __expf(-2.f * u));
          Cb[rbase + col] = f2b(g);
        }
      }
    }
  }
}

// ---------------- MFMA fused attention (bf16 qkv input) ----------------
__global__ __launch_bounds__(512) void attn_mfma(const unsigned short* __restrict__ qkvb,
                                                 unsigned short* __restrict__ ob){
  __shared__ unsigned short Ks[208*64];        // 26 KB
  __shared__ unsigned short Vt[64*256];        // 32 KB
  __shared__ unsigned short Ps[8*14*256];      // 56 KB
  const int hh = blockIdx.x, b = blockIdx.y;
  const int tid = threadIdx.x, w = tid >> 6, lane = tid & 63;
  const int c = lane & 15, g = lane >> 4;
  const unsigned short* base = qkvb + (size_t)b * SEQ * QKVN;
  char* KsB = (char*)Ks;
  char* VtB = (char*)Vt;
  char* PsB = (char*)(Ps + w * 3584);          // 7168 B per wave

  for (int i = tid; i < 3584; i += 512) ((uint4*)Ps)[i] = make_uint4(0,0,0,0);

  // stage K rows 0..207 (zero-fill >=197): byte = r*128 + ((2*d0) ^ ((r&7)<<4))
  for (int cc = tid; cc < 208*8; cc += 512){
    const int r = cc >> 3, d0 = (cc & 7) * 8;
    uint4 u = make_uint4(0,0,0,0);
    if (r < SEQ) u = *(const uint4*)(base + (size_t)r*QKVN + DIM + hh*HSZ + d0);
    *(uint4*)(KsB + r*128 + ((d0*2) ^ ((r & 7) << 4))) = u;
  }
  // stage V transposed: byte = d*512 + ((2k) ^ ((d&7)<<4))
  for (int cc = tid; cc < 224*16; cc += 512){
    const int k = cc >> 4, d0 = (cc & 15) * 4;
    ushort4 f = make_ushort4(0,0,0,0);
    if (k < SEQ) f = *(const ushort4*)(base + (size_t)k*QKVN + 2*DIM + hh*HSZ + d0);
    *(unsigned short*)(VtB + (d0+0)*512 + ((2*k) ^ (((d0+0) & 7) << 4))) = f.x;
    *(unsigned short*)(VtB + (d0+1)*512 + ((2*k) ^ (((d0+1) & 7) << 4))) = f.y;
    *(unsigned short*)(VtB + (d0+2)*512 + ((2*k) ^ (((d0+2) & 7) << 4))) = f.z;
    *(unsigned short*)(VtB + (d0+3)*512 + ((2*k) ^ (((d0+3) & 7) << 4))) = f.w;
  }
  __syncthreads();

  const float scale = 0.125f;                  // 1/sqrt(64)
  for (int qt = w; qt < 13; qt += 8){
    const unsigned short* qp = base + (size_t)(qt*16 + c)*QKVN + hh*HSZ + g*8;
    bf16x8 qf0 = *(const bf16x8*)qp;
    bf16x8 qf1 = *(const bf16x8*)(qp + 32);
    f32x4 acc[13];
#pragma unroll
    for (int j = 0; j < 13; j++) acc[j] = f32x4{0.f, 0.f, 0.f, 0.f};
#pragma unroll
    for (int j = 0; j < 13; j++){
      const int kr = j*16 + c;
      bf16x8 k0 = *(const bf16x8*)(KsB + kr*128 + ((16*g) ^ ((kr & 7) << 4)));
      bf16x8 k1 = *(const bf16x8*)(KsB + kr*128 + ((16*g + 64) ^ ((kr & 7) << 4)));
      acc[j] = __builtin_amdgcn_mfma_f32_16x16x32_bf16(qf0, k0, acc[j], 0, 0, 0);
      acc[j] = __builtin_amdgcn_mfma_f32_16x16x32_bf16(qf1, k1, acc[j], 0, 0, 0);
    }
    // scale, then mask cols 197..207 (tile 12, c>=5)
#pragma unroll
    for (int j = 0; j < 13; j++){
      acc[j][0] *= scale; acc[j][1] *= scale; acc[j][2] *= scale; acc[j][3] *= scale;
    }
    if (c >= 5){ acc[12][0] = -1e30f; acc[12][1] = -1e30f; acc[12][2] = -1e30f; acc[12][3] = -1e30f; }
    float inv[4];
#pragma unroll
    for (int r = 0; r < 4; r++){
      float m = acc[0][r];
#pragma unroll
      for (int j = 1; j < 13; j++) m = fmaxf(m, acc[j][r]);
      m = fmaxf(m, __shfl_xor(m, 1)); m = fmaxf(m, __shfl_xor(m, 2));
      m = fmaxf(m, __shfl_xor(m, 4)); m = fmaxf(m, __shfl_xor(m, 8));
      float s = 0.f;
#pragma unroll
      for (int j = 0; j < 13; j++){ float e = __expf(acc[j][r] - m); acc[j][r] = e; s += e; }
      s += __shfl_xor(s, 1); s += __shfl_xor(s, 2); s += __shfl_xor(s, 4); s += __shfl_xor(s, 8);
      inv[r] = 1.f / s;
    }
    // write P (bf16) to per-wave LDS tiles; masked cols stay zero from init
#pragma unroll
    for (int j = 0; j < 13; j++){
#pragma unroll
      for (int r = 0; r < 4; r++){
        if (j < 12 || c < 5){
          const int row = g*4 + r;
          *(unsigned short*)(PsB + j*512 + (row & 3)*128 + (row >> 2)*32 + 2*c) = f2b(acc[j][r]);
        }
      }
    }
    asm volatile("s_waitcnt lgkmcnt(0)" ::: "memory");
    __builtin_amdgcn_sched_barrier(0);
    // PV: O[16][64] = P[16][224] @ V[224][64]
    f32x4 oacc[4];
#pragma unroll
    for (int dt = 0; dt < 4; dt++) oacc[dt] = f32x4{0.f, 0.f, 0.f, 0.f};
#pragma unroll
    for (int ks = 0; ks < 7; ks++){
      const int j = 2*ks + (g >> 1);
      bf16x8 pf = *(const bf16x8*)(PsB + j*512 + (c & 3)*128 + (c >> 2)*32 + 16*(g & 1));
#pragma unroll
      for (int dt = 0; dt < 4; dt++){
        const int d = dt*16 + c;
        bf16x8 vf = *(const bf16x8*)(VtB + d*512 + ((16*g + 64*ks) ^ ((d & 7) << 4)));
        oacc[dt] = __builtin_amdgcn_mfma_f32_16x16x32_bf16(pf, vf, oacc[dt], 0, 0, 0);
      }
    }
#pragma unroll
    for (int dt = 0; dt < 4; dt++){
#pragma unroll
      for (int r = 0; r < 4; r++){
        const int rt = qt*16 + g*4 + r;
        if (rt < SEQ)
          ob[(size_t)(b*SEQ + rt)*DIM + hh*HSZ + dt*16 + c] = f2b(oacc[dt][r] * inv[r]);
      }
    }
  }
}

// ---------------- classifier ----------------
__global__ void classifier(const float* __restrict__ h, const float* __restrict__ cw,
                           const float* __restrict__ cb, float* __restrict__ out){
  const int b = blockIdx.x, tid = threadIdx.x, lane = tid & 63, wave = tid >> 6;
  const float* p = h + (size_t)b * SEQ * DIM;    // CLS row
  float s = 0.f;
  for (int c = tid; c < DIM; c += 256) s += p[c] * cw[c];
#pragma unroll
  for (int off = 32; off; off >>= 1) s += __shfl_xor(s, off);
  __shared__ float red[4];
  if (lane == 0) red[wave] = s;
  __syncthreads();
  if (tid == 0) out[b] = red[0] + red[1] + red[2] + red[3] + cb[0];
}

// ---------------- launch ----------------
extern "C" void kernel_launch(void* const* d_in, const int* in_sizes, int n_in,
                              void* d_out, int out_size, void* d_ws, size_t ws_size,
                              hipStream_t stream)
{
  (void)in_sizes; (void)n_in; (void)out_size; (void)ws_size;
  const float* x      = (const float*)d_in[0];
  const float* conv_w = (const float*)d_in[1];
  const float* conv_b = (const float*)d_in[2];
  const float* cls_tk = (const float*)d_in[3];
  const float* pos    = (const float*)d_in[4];
  const float* ln1w   = (const float*)d_in[5];
  const float* ln1b   = (const float*)d_in[6];
  const float* wq     = (const float*)d_in[7];
  const float* bq     = (const float*)d_in[8];
  const float* wk     = (const float*)d_in[9];
  const float* bk     = (const float*)d_in[10];
  const float* wv     = (const float*)d_in[11];
  const float* bv     = (const float*)d_in[12];
  const float* wo     = (const float*)d_in[13];
  const float* bo     = (const float*)d_in[14];
  const float* ln2w   = (const float*)d_in[15];
  const float* ln2b   = (const float*)d_in[16];
  const float* w1     = (const float*)d_in[17];
  const float* b1     = (const float*)d_in[18];
  const float* w2     = (const float*)d_in[19];
  const float* b2     = (const float*)d_in[20];
  const float* cls_w  = (const float*)d_in[21];
  const float* cls_b  = (const float*)d_in[22];
  float* out = (float*)d_out;

  char* wp = (char*)d_ws;
  auto take = [&](size_t bytes) -> void* {
    void* p = (void*)wp;
    wp += (bytes + 255) & ~(size_t)255;
    return p;
  };
  unsigned short* wtA  = (unsigned short*)take((size_t)LAYERS*4*KN*2);
  unsigned short* wt1  = (unsigned short*)take((size_t)LAYERS*DIM*HIDDEN*2);
  unsigned short* wt2  = (unsigned short*)take((size_t)LAYERS*DIM*HIDDEN*2);
  unsigned short* cwb  = (unsigned short*)take((size_t)KN*2);
  float*          bqkv = (float*)take((size_t)LAYERS*QKVN*4);
  unsigned short* pat  = (unsigned short*)take((size_t)MPATCH*DIM*2);
  float*          pemb = (float*)take((size_t)MPATCH*DIM*4);
  float*          h    = (float*)take((size_t)MPAD*DIM*4);
  unsigned short* hn   = (unsigned short*)take((size_t)MPAD*DIM*2);
  unsigned short* qkvb = (unsigned short*)take((size_t)MPAD*QKVN*2);
  unsigned short* ob   = (unsigned short*)take((size_t)MPAD*DIM*2);
  unsigned short* mid  = (unsigned short*)take((size_t)MPAD*HIDDEN*2);

  transpose_cast<<<dim3(DIM/32, DIM/32, LAYERS), 256, 0, stream>>>(wq, wtA + 0*KN, DIM, DIM, (size_t)KN, (size_t)4*KN);
  transpose_cast<<<dim3(DIM/32, DIM/32, LAYERS), 256, 0, stream>>>(wk, wtA + 1*KN, DIM, DIM, (size_t)KN, (size_t)4*KN);
  transpose_cast<<<dim3(DIM/32, DIM/32, LAYERS), 256, 0, stream>>>(wv, wtA + 2*KN, DIM, DIM, (size_t)KN, (size_t)4*KN);
  transpose_cast<<<dim3(DIM/32, DIM/32, LAYERS), 256, 0, stream>>>(wo, wtA + 3*KN, DIM, DIM, (size_t)KN, (size_t)4*KN);
  transpose_cast<<<dim3(DIM/32, HIDDEN/32, LAYERS), 256, 0, stream>>>(w1, wt1, DIM, HIDDEN, (size_t)DIM*HIDDEN, (size_t)DIM*HIDDEN);
  transpose_cast<<<dim3(HIDDEN/32, DIM/32, LAYERS), 256, 0, stream>>>(w2, wt2, HIDDEN, DIM, (size_t)DIM*HIDDEN, (size_t)DIM*HIDDEN);
  cast_bf16<<<(KN + 255)/256, 256, 0, stream>>>(conv_w, cwb, KN);
  pack_bias<<<(LAYERS*QKVN + 255)/256, 256, 0, stream>>>(bq, bk, bv, bqkv);

  patchify<<<dim3(MPATCH, 3), 256, 0, stream>>>(x, pat);
  gemm_bt<EPI_F32,64><<<dim3(DIM/64, MPATCH/128), 256, 0, stream>>>(pat, cwb, conv_b, nullptr, pemb, nullptr, DIM, DIM);
  assemble<<<dim3(MREAL, 3), 256, 0, stream>>>(pemb, cls_tk, pos, h);

  for (int l = 0; l < LAYERS; ++l){
    ln_bf16<<<MREAL/4, 256, 0, stream>>>(h, ln1w + l*DIM, ln1b + l*DIM, hn, MREAL);
    gemm_bt<EPI_B16,128><<<dim3(QKVN/128, MPAD/128), 256, 0, stream>>>(
        hn, wtA + (size_t)l*4*KN, bqkv + l*QKVN, nullptr, nullptr, qkvb, DIM, QKVN);
    attn_mfma<<<dim3(NHEAD, BATCH), 512, 0, stream>>>(qkvb, ob);
    gemm_bt<EPI_RES,64><<<dim3(DIM/64, MPAD/128), 256, 0, stream>>>(
        ob, wtA + ((size_t)l*4 + 3)*KN, bo + l*DIM, h, h, nullptr, DIM, DIM);
    ln_bf16<<<MREAL/4, 256, 0, stream>>>(h, ln2w + l*DIM, ln2b + l*DIM, hn, MREAL);
    gemm_bt<EPI_GELU,128><<<dim3(HIDDEN/128, MPAD/128), 256, 0, stream>>>(
        hn, wt1 + (size_t)l*DIM*HIDDEN, b1 + l*HIDDEN, nullptr, nullptr, mid, DIM, HIDDEN);
    gemm_bt<EPI_RES,64><<<dim3(DIM/64, MPAD/128), 256, 0, stream>>>(
        mid, wt2 + (size_t)l*DIM*HIDDEN, b2 + l*DIM, h, h, nullptr, HIDDEN, DIM);
  }

  classifier<<<BATCH, 256, 0, stream>>>(h, cls_w, cls_b, out);
}